// Round 2
// baseline (206.573 us; speedup 1.0000x reference)
//
#include <hip/hip_runtime.h>
#include <hip/hip_bf16.h>

#define B_ 2
#define S_ 2048
#define D_ 1024
#define H_ 16
#define HD_ 64

// Q is pre-scaled by 0.125 * log2(e) at projection time; attention runs in
// log2 domain: p = exp2(qk_scaled + (mask_k - 1) * 10000 * log2(e)).
// Mask enters as the MFMA C-initializer (bias per key), so masked keys give
// p = exp2(-huge) = 0 in BOTH numerator and denominator.
#define QSCALE 0.18033688f
#define MLOG2E 14426.950408f

// HW exp2: v_exp_f32 computes 2^x directly.
#define EXP2(x) __builtin_amdgcn_exp2f(x)

typedef __attribute__((ext_vector_type(8))) short bf16x8;
typedef __attribute__((ext_vector_type(4))) short short4v;
typedef __attribute__((ext_vector_type(4))) float floatx4;
typedef __attribute__((ext_vector_type(16))) float f32x16;

static __device__ __forceinline__ short f2bf(float f) {
  union { float f; unsigned int i; } c; c.f = f;
  unsigned int r = c.i + 0x7FFFu + ((c.i >> 16) & 1u);
  return (short)(r >> 16);
}

// v_cvt_pk_bf16_f32: lo16 = bf16(a), hi16 = bf16(b). No builtin on gfx950.
static __device__ __forceinline__ int cvtpk_bf16(float a, float b) {
  int r;
  asm("v_cvt_pk_bf16_f32 %0, %1, %2" : "=v"(r) : "v"(a), "v"(b));
  return r;
}
// v_permlane32_swap_b32: a.lanes[32:63] <-> b.lanes[0:31]; both updated.
static __device__ __forceinline__ void swap32(int& a, int& b) {
  asm("v_permlane32_swap_b32 %0, %1" : "+v"(a), "+v"(b));
}

static __device__ __forceinline__ void gld_lds16(const void* g, void* l) {
  __builtin_amdgcn_global_load_lds(
      (const __attribute__((address_space(1))) unsigned int*)g,
      (__attribute__((address_space(3))) unsigned int*)l, 16, 0, 0);
}

// ---------------- prep: weight transposes (z<4) + hs fp32->bf16 (z==4) ------
__global__ __launch_bounds__(256)
void prep(const float* __restrict__ w0, const float* __restrict__ w1,
          const float* __restrict__ w2, const float* __restrict__ w3,
          const float* __restrict__ hs, short* __restrict__ WT,
          short* __restrict__ Xb) {
  const int z = blockIdx.z;
  if (z < 4) {
    __shared__ short t[64][65];
    const float* src = z == 0 ? w0 : z == 1 ? w1 : z == 2 ? w2 : w3;
    short* dst = WT + (size_t)z * D_ * D_;
    const int tx = threadIdx.x & 63, ty = threadIdx.x >> 6;
    const int r0 = blockIdx.y * 64, c0 = blockIdx.x * 64;
    for (int r = ty; r < 64; r += 4)
      t[r][tx] = f2bf(src[(size_t)(r0 + r) * D_ + c0 + tx]);
    __syncthreads();
    for (int r = ty; r < 64; r += 4)
      dst[(size_t)(c0 + r) * D_ + r0 + tx] = t[tx][r];
  } else {
    const int bid = blockIdx.y * 16 + blockIdx.x;
    const float4* in4 = (const float4*)hs;
    short4v* out4 = (short4v*)Xb;
#pragma unroll
    for (int i = 0; i < 16; i++) {
      const int idx = bid * 4096 + i * 256 + threadIdx.x;
      const float4 v = in4[idx];
      short4v o;
      o[0] = f2bf(v.x); o[1] = f2bf(v.y); o[2] = f2bf(v.z); o[3] = f2bf(v.w);
      out4[idx] = o;
    }
  }
}

// ---------------- fused QKV projection (single launch) ----------------
// widx 0/1 (Q,K): operand-swapped MFMA -> C^T, b64 stores to [B,H,S,HD].
// widx 2 (V): normal orientation -> V^T [B,H,HD,S] (mask handled in attn).
__global__ __launch_bounds__(256, 2)
void gemm_qkv(const short* __restrict__ X, const short* __restrict__ WT,
              const float* __restrict__ qb, const float* __restrict__ kb,
              const float* __restrict__ vb,
              short* __restrict__ Qo, short* __restrict__ Ko,
              short* __restrict__ Vt) {
  __shared__ __align__(16) short As[128 * 32];
  __shared__ __align__(16) short Bs[128 * 32];
  const int tid = threadIdx.x;
  const int wave = tid >> 6, lane = tid & 63;
  const int col = lane & 15, quad = lane >> 4;
  const int m0 = blockIdx.x * 128;          // seq offset
  const int nt = blockIdx.y;
  const int widx = nt >> 3;                 // 0=Q 1=K 2=V
  const int n1 = (nt & 7) * 128;            // feature offset
  const short* Bsrc = WT + (size_t)widx * D_ * D_ + (size_t)n1 * D_;
  const int b = m0 >> 11;

  const int srow = tid >> 2;
  const int skcol = (tid & 3) * 8;
  const short* ga = X + (size_t)(m0 + srow) * D_ + skcol;
  const short* gb = Bsrc + (size_t)srow * D_ + skcol;
  short* la = As + tid * 8;
  short* lb = Bs + tid * 8;

  floatx4 acc[4][4];
#pragma unroll
  for (int i = 0; i < 4; i++)
#pragma unroll
    for (int j = 0; j < 4; j++) acc[i][j] = floatx4{0.f, 0.f, 0.f, 0.f};

  if (widx < 2) {  // ---- Q/K: swapped operands -> C^T ----
    const int wseq = (wave >> 1) * 64;
    const int wfeat = (wave & 1) * 64;
    for (int k0 = 0; k0 < D_; k0 += 32) {
      gld_lds16(ga, la);
      gld_lds16(ga + 64 * D_, la + 2048);
      gld_lds16(gb, lb);
      gld_lds16(gb + 64 * D_, lb + 2048);
      ga += 32; gb += 32;
      __syncthreads();
      bf16x8 xf[4], wf[4];
#pragma unroll
      for (int j = 0; j < 4; j++)
        xf[j] = *(const bf16x8*)(As + (wseq + j * 16 + col) * 32 + quad * 8);
#pragma unroll
      for (int i = 0; i < 4; i++)
        wf[i] = *(const bf16x8*)(Bs + (wfeat + i * 16 + col) * 32 + quad * 8);
#pragma unroll
      for (int i = 0; i < 4; i++)
#pragma unroll
        for (int j = 0; j < 4; j++)
          acc[i][j] = __builtin_amdgcn_mfma_f32_16x16x32_bf16(wf[i], xf[j],
                                                              acc[i][j], 0, 0, 0);
      __syncthreads();
    }
    const float* bias = widx == 0 ? qb : kb;
    short* dst = widx == 0 ? Qo : Ko;
    const float scale = widx == 0 ? QSCALE : 1.0f;
#pragma unroll
    for (int i = 0; i < 4; i++) {
      const int nf = n1 + wfeat + i * 16 + quad * 4;  // 4 consecutive features
      const int h = nf >> 6, hd = nf & 63;
      const float4 bv = *(const float4*)(bias + nf);
#pragma unroll
      for (int j = 0; j < 4; j++) {
        const int s = (m0 + wseq + j * 16 + col) & (S_ - 1);
        short4v pk;
        pk[0] = f2bf((acc[i][j][0] + bv.x) * scale);
        pk[1] = f2bf((acc[i][j][1] + bv.y) * scale);
        pk[2] = f2bf((acc[i][j][2] + bv.z) * scale);
        pk[3] = f2bf((acc[i][j][3] + bv.w) * scale);
        *(short4v*)(dst + ((size_t)(b * H_ + h) * S_ + s) * HD_ + hd) = pk;
      }
    }
  } else {  // ---- V: normal orientation, V^T output ----
    const int wrow = (wave & 1) * 64;
    const int wcol = (wave >> 1) * 64;
    for (int k0 = 0; k0 < D_; k0 += 32) {
      gld_lds16(ga, la);
      gld_lds16(ga + 64 * D_, la + 2048);
      gld_lds16(gb, lb);
      gld_lds16(gb + 64 * D_, lb + 2048);
      ga += 32; gb += 32;
      __syncthreads();
      bf16x8 af[4], bfr[4];
#pragma unroll
      for (int i = 0; i < 4; i++)
        af[i] = *(const bf16x8*)(As + (wrow + i * 16 + col) * 32 + quad * 8);
#pragma unroll
      for (int j = 0; j < 4; j++)
        bfr[j] = *(const bf16x8*)(Bs + (wcol + j * 16 + col) * 32 + quad * 8);
#pragma unroll
      for (int i = 0; i < 4; i++)
#pragma unroll
        for (int j = 0; j < 4; j++)
          acc[i][j] = __builtin_amdgcn_mfma_f32_16x16x32_bf16(af[i], bfr[j],
                                                              acc[i][j], 0, 0, 0);
      __syncthreads();
    }
    float bv[4];
#pragma unroll
    for (int j = 0; j < 4; j++) bv[j] = vb[n1 + wcol + j * 16 + col];
#pragma unroll
    for (int i = 0; i < 4; i++) {
      const int s = (m0 + wrow + i * 16 + quad * 4) & (S_ - 1);
#pragma unroll
      for (int j = 0; j < 4; j++) {
        const int nl = n1 + wcol + j * 16 + col;
        const int h = nl >> 6, hd = nl & 63;
        short4v pk;
#pragma unroll
        for (int r = 0; r < 4; r++) pk[r] = f2bf(acc[i][j][r] + bv[j]);
        *(short4v*)(Vt + ((size_t)(b * H_ + h) * HD_ + hd) * S_ + s) = pk;
      }
    }
  }
}

// ---------------- flash attention v3: 4 independent blocks/CU ---------------
// r1 counters showed sum-of-pipes (MFMA 28% + VALU 27% + LDS ~35%) with 2
// barrier-locked waves/SIMD -> phase-serialized. v3: 1024 blocks x 128 thr
// (2 waves, 64 q-rows), 32KB LDS -> 4 INDEPENDENT blocks/CU. Blocks drift ->
// one block's MFMA overlaps another's exp2/LDS on the same SIMD. Per-block
// key-start offset decorrelates same-head blocks (softmax is an order-
// independent exp2-sum). setprio(1) wraps MFMA clusters (T5: pays with
// phase-diverse co-resident waves). Mask bias read from global (L1-hot 8KB).
__global__ __launch_bounds__(128, 2)
void attn(const short* __restrict__ Q, const short* __restrict__ K,
          const short* __restrict__ Vt, const float* __restrict__ mask,
          short* __restrict__ ctx) {
  __shared__ __align__(16) short Ks[2][4096];   // 16 KB: [64 key][8 chunk swz]
  __shared__ __align__(16) short Vs[2][4096];   // 16 KB: [64 hd][8 chunk swz]
  const int tid = threadIdx.x, wave = tid >> 6, lane = tid & 63;
  const int l31 = lane & 31, hi = lane >> 5, x7 = l31 & 7;
  const int lin = blockIdx.x;
  const int qt = (lin >> 3) & 31;                 // 32 q-tiles of 64 rows
  const int gi = (lin & 7) | ((lin >> 8) << 3);   // XCD = lin%8, const per head
  const int h = gi & 15, b = gi >> 4;
  const short* Qh = Q + (size_t)(b * H_ + h) * S_ * HD_;
  const short* Kh = K + (size_t)(b * H_ + h) * S_ * HD_;
  const short* Vh = Vt + (size_t)(b * H_ + h) * HD_ * S_;
  const float* mk = mask + (size_t)b * S_;
  const int q0 = qt * 64 + wave * 32;

  // staging: thread t, sub i -> slot s = t + i*128; row = s>>3, chunk (s&7)^(row&7)
  int srow[4], schk[4];
#pragma unroll
  for (int i = 0; i < 4; i++) {
    const int s = tid + i * 128;
    srow[i] = s >> 3;
    schk[i] = ((s & 7) ^ (srow[i] & 7)) * 8;
  }

  // prologue: stage tile 0 (key offset kt0) into buffer 0
  const int kt0 = qt * 64;  // per-block start offset
#pragma unroll
  for (int i = 0; i < 4; i++) {
    gld_lds16(Kh + (size_t)(kt0 + srow[i]) * HD_ + schk[i], &Ks[0][(tid + i * 128) * 8]);
    gld_lds16(Vh + (size_t)srow[i] * S_ + kt0 + schk[i], &Vs[0][(tid + i * 128) * 8]);
  }

  // Q as B-operand fragments: qf[c] = Q[q0+l31][c*16 + hi*8 .. +7]
  bf16x8 qf[4];
  {
    const short* qp = Qh + (size_t)(q0 + l31) * HD_ + hi * 8;
#pragma unroll
    for (int c = 0; c < 4; c++) qf[c] = *(const bf16x8*)(qp + c * 16);
  }

  // all-ones bf16 A-fragment for the rowsum MFMA
  bf16x8 ones;
#pragma unroll
  for (int i = 0; i < 8; i++) ones[i] = (short)0x3F80;

  f32x16 acc0, acc1, rsa;
#pragma unroll
  for (int r = 0; r < 16; r++) { acc0[r] = 0.f; acc1[r] = 0.f; rsa[r] = 0.f; }

  // per-lane fragment slot offsets (in shorts): chunk w lives at slot w^x7
  const int kbase = l31 * 64;
  int ko[4];
#pragma unroll
  for (int c = 0; c < 4; c++) ko[c] = ((((c << 1) | hi) ^ x7) << 3);

  __syncthreads();  // tile 0 staged

  for (int it = 0; it < S_ / 64; it++) {
    const int buf = it & 1;
    const int kt = ((it + qt) & 31) * 64;
    if (it + 1 < S_ / 64) {  // issue next tile's staging
      const int kn = ((it + 1 + qt) & 31) * 64;
#pragma unroll
      for (int i = 0; i < 4; i++) {
        gld_lds16(Kh + (size_t)(kn + srow[i]) * HD_ + schk[i],
                  &Ks[buf ^ 1][(tid + i * 128) * 8]);
        gld_lds16(Vh + (size_t)srow[i] * S_ + kn + schk[i],
                  &Vs[buf ^ 1][(tid + i * 128) * 8]);
      }
    }

    bf16x8 pB[4];  // PV B-fragments, key chunks kc: keys kt + kc*16 + hi*8 + j
#pragma unroll
    for (int t = 0; t < 2; t++) {
      // bias-seeded C: z[r] = bias[kt + t*32 + crow(r,hi)] (L1-hot float4s)
      const int kb2 = kt + t * 32 + 4 * hi;
      const float4 b0 = *(const float4*)&mk[kb2];
      const float4 b1 = *(const float4*)&mk[kb2 + 8];
      const float4 b2 = *(const float4*)&mk[kb2 + 16];
      const float4 b3 = *(const float4*)&mk[kb2 + 24];
      f32x16 z;
      z[0]  = (b0.x - 1.0f) * MLOG2E; z[1]  = (b0.y - 1.0f) * MLOG2E;
      z[2]  = (b0.z - 1.0f) * MLOG2E; z[3]  = (b0.w - 1.0f) * MLOG2E;
      z[4]  = (b1.x - 1.0f) * MLOG2E; z[5]  = (b1.y - 1.0f) * MLOG2E;
      z[6]  = (b1.z - 1.0f) * MLOG2E; z[7]  = (b1.w - 1.0f) * MLOG2E;
      z[8]  = (b2.x - 1.0f) * MLOG2E; z[9]  = (b2.y - 1.0f) * MLOG2E;
      z[10] = (b2.z - 1.0f) * MLOG2E; z[11] = (b2.w - 1.0f) * MLOG2E;
      z[12] = (b3.x - 1.0f) * MLOG2E; z[13] = (b3.y - 1.0f) * MLOG2E;
      z[14] = (b3.z - 1.0f) * MLOG2E; z[15] = (b3.w - 1.0f) * MLOG2E;
      const short* kp = &Ks[buf][t * 2048 + kbase];
      __builtin_amdgcn_s_setprio(1);
#pragma unroll
      for (int c = 0; c < 4; c++) {
        const bf16x8 kf = *(const bf16x8*)(kp + ko[c]);
        z = __builtin_amdgcn_mfma_f32_32x32x16_bf16(kf, qf[c], z, 0, 0, 0);
      }
      __builtin_amdgcn_s_setprio(0);
      float p[16];
#pragma unroll
      for (int r = 0; r < 16; r++) p[r] = EXP2(z[r]);
      // pack pairs (keys 2m,2m+1 within each 8-key group) then half-swap:
      // a* hold keys {4hi..4hi+3}, c* keys {8+4hi..}, e* {16+4hi..}, g* {24+4hi..}
      int a0 = cvtpk_bf16(p[0], p[1]),   a1 = cvtpk_bf16(p[2], p[3]);
      int cc0 = cvtpk_bf16(p[4], p[5]),  cc1 = cvtpk_bf16(p[6], p[7]);
      int e0 = cvtpk_bf16(p[8], p[9]),   e1 = cvtpk_bf16(p[10], p[11]);
      int g0 = cvtpk_bf16(p[12], p[13]), g1 = cvtpk_bf16(p[14], p[15]);
      swap32(a0, cc0); swap32(a1, cc1);  // -> chunk 2t words {0,1,2,3}
      swap32(e0, g0);  swap32(e1, g1);   // -> chunk 2t+1 words {0,1,2,3}
      union { int i[4]; bf16x8 v; } u0, u1;
      u0.i[0] = a0; u0.i[1] = a1; u0.i[2] = cc0; u0.i[3] = cc1;
      u1.i[0] = e0; u1.i[1] = e1; u1.i[2] = g0;  u1.i[3] = g1;
      pB[t * 2] = u0.v;
      pB[t * 2 + 1] = u1.v;
    }

    // rowsum + PV under raised priority (MFMA cluster)
    const short* vp0 = &Vs[buf][kbase];          // hd rows l31
    const short* vp1 = &Vs[buf][2048 + kbase];   // hd rows 32+l31
    __builtin_amdgcn_s_setprio(1);
#pragma unroll
    for (int kc = 0; kc < 4; kc++)
      rsa = __builtin_amdgcn_mfma_f32_32x32x16_bf16(ones, pB[kc], rsa, 0, 0, 0);
#pragma unroll
    for (int kc = 0; kc < 4; kc++) {
      const bf16x8 vf0 = *(const bf16x8*)(vp0 + ko[kc]);
      const bf16x8 vf1 = *(const bf16x8*)(vp1 + ko[kc]);
      acc0 = __builtin_amdgcn_mfma_f32_32x32x16_bf16(vf0, pB[kc], acc0, 0, 0, 0);
      acc1 = __builtin_amdgcn_mfma_f32_32x32x16_bf16(vf1, pB[kc], acc1, 0, 0, 0);
    }
    __builtin_amdgcn_s_setprio(0);
    __syncthreads();  // compute reads done; next staging landed
  }

  // epilogue: acc reg r -> ctx[q=l31][hd = d*32 + (r&3) + 8*(r>>2) + 4*hi]
  const float inv = 1.0f / (rsa[0] + 1e-30f);
  const size_t row = (size_t)b * S_ + q0 + l31;
#pragma unroll
  for (int g4 = 0; g4 < 4; g4++) {
    short4v o0, o1;
#pragma unroll
    for (int j = 0; j < 4; j++) {
      o0[j] = f2bf(acc0[g4 * 4 + j] * inv);
      o1[j] = f2bf(acc1[g4 * 4 + j] * inv);
    }
    short* cp = ctx + row * D_ + h * HD_ + g4 * 8 + 4 * hi;
    *(short4v*)(cp) = o0;
    *(short4v*)(cp + 32) = o1;
  }
}

// ---------------- output projection: 64x128 tile, grid 512 (2 blocks/CU) ----
__global__ __launch_bounds__(256, 2)
void gemm_out(const short* __restrict__ X, const short* __restrict__ WT,
              const float* __restrict__ ob, float* __restrict__ out) {
  __shared__ __align__(16) short As[64 * 32];    // 4 KB
  __shared__ __align__(16) short Bs[128 * 32];   // 8 KB
  const int tid = threadIdx.x;
  const int wave = tid >> 6, lane = tid & 63;
  const int col = lane & 15, quad = lane >> 4;
  const int m0 = blockIdx.x * 64;
  const int n0 = blockIdx.y * 128;
  const short* Bsrc = WT + (size_t)n0 * D_;
  const int wrow = (wave & 1) * 32;
  const int wcol = (wave >> 1) * 64;

  floatx4 acc[2][4];
#pragma unroll
  for (int i = 0; i < 2; i++)
#pragma unroll
    for (int j = 0; j < 4; j++) acc[i][j] = floatx4{0.f, 0.f, 0.f, 0.f};

  const int arow = tid >> 2, akcol = (tid & 3) * 8;
  const short* ga = X + (size_t)(m0 + arow) * D_ + akcol;
  const short* gb = Bsrc + (size_t)arow * D_ + akcol;
  short* la = As + tid * 8;
  short* lb = Bs + tid * 8;

  for (int k0 = 0; k0 < D_; k0 += 32) {
    gld_lds16(ga, la);
    gld_lds16(gb, lb);
    gld_lds16(gb + 64 * D_, lb + 2048);
    ga += 32; gb += 32;
    __syncthreads();
    bf16x8 af[2], bfr[4];
#pragma unroll
    for (int i = 0; i < 2; i++)
      af[i] = *(const bf16x8*)(As + (wrow + i * 16 + col) * 32 + quad * 8);
#pragma unroll
    for (int j = 0; j < 4; j++)
      bfr[j] = *(const bf16x8*)(Bs + (wcol + j * 16 + col) * 32 + quad * 8);
#pragma unroll
    for (int i = 0; i < 2; i++)
#pragma unroll
      for (int j = 0; j < 4; j++)
        acc[i][j] = __builtin_amdgcn_mfma_f32_16x16x32_bf16(af[i], bfr[j],
                                                            acc[i][j], 0, 0, 0);
    __syncthreads();
  }

  float bv[4];
#pragma unroll
  for (int j = 0; j < 4; j++) bv[j] = ob[n0 + wcol + j * 16 + col];

#pragma unroll
  for (int i = 0; i < 2; i++) {
    const int m = m0 + wrow + i * 16 + quad * 4;
#pragma unroll
    for (int j = 0; j < 4; j++) {
      const int n = n0 + wcol + j * 16 + col;
#pragma unroll
      for (int r = 0; r < 4; r++)
        out[(size_t)(m + r) * D_ + n] = acc[i][j][r] + bv[j];
    }
  }
}

extern "C" void kernel_launch(void* const* d_in, const int* in_sizes, int n_in,
                              void* d_out, int out_size, void* d_ws, size_t ws_size,
                              hipStream_t stream) {
  (void)in_sizes; (void)n_in; (void)out_size; (void)ws_size;
  const float* hs  = (const float*)d_in[0];
  const float* msk = (const float*)d_in[1];
  const float* qw  = (const float*)d_in[2];
  const float* qb  = (const float*)d_in[3];
  const float* kw  = (const float*)d_in[4];
  const float* kb  = (const float*)d_in[5];
  const float* vw  = (const float*)d_in[6];
  const float* vb  = (const float*)d_in[7];
  const float* ow  = (const float*)d_in[8];
  const float* ob  = (const float*)d_in[9];
  float* out = (float*)d_out;
  char* ws = (char*)d_ws;

  short* Xb  = (short*)(ws);                    // bf16 hs (8 MB); reused as Ctx
  short* WT  = (short*)(ws + (8ull  << 20));    // 4 x 1024x1024 bf16 (8 MB)
  short* Qp  = (short*)(ws + (16ull << 20));    // [B,H,S,HD] (8 MB)
  short* Kp  = (short*)(ws + (24ull << 20));    // [B,H,S,HD] (8 MB)
  short* Vtp = (short*)(ws + (32ull << 20));    // [B,H,HD,S] (8 MB)
  short* Ctx = Xb;                              // [B,S,D] bf16 (overlays Xb)

  prep<<<dim3(16, 16, 5), 256, 0, stream>>>(qw, kw, vw, ow, hs, WT, Xb);
  gemm_qkv<<<dim3(32, 24), 256, 0, stream>>>(Xb, WT, qb, kb, vb, Qp, Kp, Vtp);
  attn<<<dim3(1024), 128, 0, stream>>>(Qp, Kp, Vtp, msk, Ctx);
  gemm_out<<<dim3(64, 8), 256, 0, stream>>>(Ctx, WT + 3ull * D_ * D_, ob, out);
}

// Round 3
// 190.530 us; speedup vs baseline: 1.0842x; 1.0842x over previous
//
#include <hip/hip_runtime.h>
#include <hip/hip_bf16.h>

#define B_ 2
#define S_ 2048
#define D_ 1024
#define H_ 16
#define HD_ 64

// Q is pre-scaled by 0.125 * log2(e) at projection time; attention runs in
// log2 domain: p = exp2(qk_scaled + (mask_k - 1) * 10000 * log2(e)).
// Mask enters as the MFMA C-initializer (bias per key), so masked keys give
// p = exp2(-huge) = 0 in BOTH numerator and denominator.
#define QSCALE 0.18033688f
#define MLOG2E 14426.950408f

// HW exp2: v_exp_f32 computes 2^x directly.
#define EXP2(x) __builtin_amdgcn_exp2f(x)

typedef __attribute__((ext_vector_type(8))) short bf16x8;
typedef __attribute__((ext_vector_type(4))) short short4v;
typedef __attribute__((ext_vector_type(4))) float floatx4;
typedef __attribute__((ext_vector_type(16))) float f32x16;

static __device__ __forceinline__ short f2bf(float f) {
  union { float f; unsigned int i; } c; c.f = f;
  unsigned int r = c.i + 0x7FFFu + ((c.i >> 16) & 1u);
  return (short)(r >> 16);
}

// v_cvt_pk_bf16_f32: lo16 = bf16(a), hi16 = bf16(b). No builtin on gfx950.
static __device__ __forceinline__ int cvtpk_bf16(float a, float b) {
  int r;
  asm("v_cvt_pk_bf16_f32 %0, %1, %2" : "=v"(r) : "v"(a), "v"(b));
  return r;
}
// v_permlane32_swap_b32: a.lanes[32:63] <-> b.lanes[0:31]; both updated.
static __device__ __forceinline__ void swap32(int& a, int& b) {
  asm("v_permlane32_swap_b32 %0, %1" : "+v"(a), "+v"(b));
}

static __device__ __forceinline__ void gld_lds16(const void* g, void* l) {
  __builtin_amdgcn_global_load_lds(
      (const __attribute__((address_space(1))) unsigned int*)g,
      (__attribute__((address_space(3))) unsigned int*)l, 16, 0, 0);
}

// ---------------- prep: weight transposes (z<4) + hs fp32->bf16 (z==4) ------
__global__ __launch_bounds__(256)
void prep(const float* __restrict__ w0, const float* __restrict__ w1,
          const float* __restrict__ w2, const float* __restrict__ w3,
          const float* __restrict__ hs, short* __restrict__ WT,
          short* __restrict__ Xb) {
  const int z = blockIdx.z;
  if (z < 4) {
    __shared__ short t[64][65];
    const float* src = z == 0 ? w0 : z == 1 ? w1 : z == 2 ? w2 : w3;
    short* dst = WT + (size_t)z * D_ * D_;
    const int tx = threadIdx.x & 63, ty = threadIdx.x >> 6;
    const int r0 = blockIdx.y * 64, c0 = blockIdx.x * 64;
    for (int r = ty; r < 64; r += 4)
      t[r][tx] = f2bf(src[(size_t)(r0 + r) * D_ + c0 + tx]);
    __syncthreads();
    for (int r = ty; r < 64; r += 4)
      dst[(size_t)(c0 + r) * D_ + r0 + tx] = t[tx][r];
  } else {
    const int bid = blockIdx.y * 16 + blockIdx.x;
    const float4* in4 = (const float4*)hs;
    short4v* out4 = (short4v*)Xb;
#pragma unroll
    for (int i = 0; i < 16; i++) {
      const int idx = bid * 4096 + i * 256 + threadIdx.x;
      const float4 v = in4[idx];
      short4v o;
      o[0] = f2bf(v.x); o[1] = f2bf(v.y); o[2] = f2bf(v.z); o[3] = f2bf(v.w);
      out4[idx] = o;
    }
  }
}

// ---------------- fused QKV projection (single launch) ----------------
// widx 0/1 (Q,K): operand-swapped MFMA -> C^T, b64 stores to [B,H,S,HD].
// widx 2 (V): normal orientation -> V^T [B,H,HD,S] (mask handled in attn).
__global__ __launch_bounds__(256, 2)
void gemm_qkv(const short* __restrict__ X, const short* __restrict__ WT,
              const float* __restrict__ qb, const float* __restrict__ kb,
              const float* __restrict__ vb,
              short* __restrict__ Qo, short* __restrict__ Ko,
              short* __restrict__ Vt) {
  __shared__ __align__(16) short As[128 * 32];
  __shared__ __align__(16) short Bs[128 * 32];
  const int tid = threadIdx.x;
  const int wave = tid >> 6, lane = tid & 63;
  const int col = lane & 15, quad = lane >> 4;
  const int m0 = blockIdx.x * 128;          // seq offset
  const int nt = blockIdx.y;
  const int widx = nt >> 3;                 // 0=Q 1=K 2=V
  const int n1 = (nt & 7) * 128;            // feature offset
  const short* Bsrc = WT + (size_t)widx * D_ * D_ + (size_t)n1 * D_;
  const int b = m0 >> 11;

  const int srow = tid >> 2;
  const int skcol = (tid & 3) * 8;
  const short* ga = X + (size_t)(m0 + srow) * D_ + skcol;
  const short* gb = Bsrc + (size_t)srow * D_ + skcol;
  short* la = As + tid * 8;
  short* lb = Bs + tid * 8;

  floatx4 acc[4][4];
#pragma unroll
  for (int i = 0; i < 4; i++)
#pragma unroll
    for (int j = 0; j < 4; j++) acc[i][j] = floatx4{0.f, 0.f, 0.f, 0.f};

  if (widx < 2) {  // ---- Q/K: swapped operands -> C^T ----
    const int wseq = (wave >> 1) * 64;
    const int wfeat = (wave & 1) * 64;
    for (int k0 = 0; k0 < D_; k0 += 32) {
      gld_lds16(ga, la);
      gld_lds16(ga + 64 * D_, la + 2048);
      gld_lds16(gb, lb);
      gld_lds16(gb + 64 * D_, lb + 2048);
      ga += 32; gb += 32;
      __syncthreads();
      bf16x8 xf[4], wf[4];
#pragma unroll
      for (int j = 0; j < 4; j++)
        xf[j] = *(const bf16x8*)(As + (wseq + j * 16 + col) * 32 + quad * 8);
#pragma unroll
      for (int i = 0; i < 4; i++)
        wf[i] = *(const bf16x8*)(Bs + (wfeat + i * 16 + col) * 32 + quad * 8);
#pragma unroll
      for (int i = 0; i < 4; i++)
#pragma unroll
        for (int j = 0; j < 4; j++)
          acc[i][j] = __builtin_amdgcn_mfma_f32_16x16x32_bf16(wf[i], xf[j],
                                                              acc[i][j], 0, 0, 0);
      __syncthreads();
    }
    const float* bias = widx == 0 ? qb : kb;
    short* dst = widx == 0 ? Qo : Ko;
    const float scale = widx == 0 ? QSCALE : 1.0f;
#pragma unroll
    for (int i = 0; i < 4; i++) {
      const int nf = n1 + wfeat + i * 16 + quad * 4;  // 4 consecutive features
      const int h = nf >> 6, hd = nf & 63;
      const float4 bv = *(const float4*)(bias + nf);
#pragma unroll
      for (int j = 0; j < 4; j++) {
        const int s = (m0 + wseq + j * 16 + col) & (S_ - 1);
        short4v pk;
        pk[0] = f2bf((acc[i][j][0] + bv.x) * scale);
        pk[1] = f2bf((acc[i][j][1] + bv.y) * scale);
        pk[2] = f2bf((acc[i][j][2] + bv.z) * scale);
        pk[3] = f2bf((acc[i][j][3] + bv.w) * scale);
        *(short4v*)(dst + ((size_t)(b * H_ + h) * S_ + s) * HD_ + hd) = pk;
      }
    }
  } else {  // ---- V: normal orientation, V^T output ----
    const int wrow = (wave & 1) * 64;
    const int wcol = (wave >> 1) * 64;
    for (int k0 = 0; k0 < D_; k0 += 32) {
      gld_lds16(ga, la);
      gld_lds16(ga + 64 * D_, la + 2048);
      gld_lds16(gb, lb);
      gld_lds16(gb + 64 * D_, lb + 2048);
      ga += 32; gb += 32;
      __syncthreads();
      bf16x8 af[4], bfr[4];
#pragma unroll
      for (int i = 0; i < 4; i++)
        af[i] = *(const bf16x8*)(As + (wrow + i * 16 + col) * 32 + quad * 8);
#pragma unroll
      for (int j = 0; j < 4; j++)
        bfr[j] = *(const bf16x8*)(Bs + (wcol + j * 16 + col) * 32 + quad * 8);
#pragma unroll
      for (int i = 0; i < 4; i++)
#pragma unroll
        for (int j = 0; j < 4; j++)
          acc[i][j] = __builtin_amdgcn_mfma_f32_16x16x32_bf16(af[i], bfr[j],
                                                              acc[i][j], 0, 0, 0);
      __syncthreads();
    }
    float bv[4];
#pragma unroll
    for (int j = 0; j < 4; j++) bv[j] = vb[n1 + wcol + j * 16 + col];
#pragma unroll
    for (int i = 0; i < 4; i++) {
      const int s = (m0 + wrow + i * 16 + quad * 4) & (S_ - 1);
#pragma unroll
      for (int j = 0; j < 4; j++) {
        const int nl = n1 + wcol + j * 16 + col;
        const int h = nl >> 6, hd = nl & 63;
        short4v pk;
#pragma unroll
        for (int r = 0; r < 4; r++) pk[r] = f2bf(acc[i][j][r] + bv[j]);
        *(short4v*)(Vt + ((size_t)(b * H_ + h) * HD_ + hd) * S_ + s) = pk;
      }
    }
  }
}

// ---------------- flash attention v4: KVBLK=128, half the barriers ----------
// v2 post-mortem: ~2800 idle cyc per 64-key barrier interval (all pipes <35%)
// = fixed per-interval cost (vmcnt drain + reconvergence + dep-chain latency).
// v4 keeps v2's verified structure (512 blocks x 4 waves x 32 q-rows, in-reg
// P via cvt_pk+permlane32, mask bias as MFMA C-seed) but processes TWO 64-key
// sub-tiles per barrier interval: 16 intervals instead of 32 -> fixed cost
// halves. Staging per unit compute unchanged (the v3 mistake avoided).
// LDS 72KB: K/V dbuf 2x(16+16)KB + Wb 8KB -> 2 blocks/CU.
__global__ __launch_bounds__(256, 2)
void attn(const short* __restrict__ Q, const short* __restrict__ K,
          const short* __restrict__ Vt, const float* __restrict__ mask,
          short* __restrict__ ctx) {
  __shared__ __align__(16) short Ks[2][8192];   // 32 KB: [buf][ts*4096 + row*64 + slot*8]
  __shared__ __align__(16) short Vs[2][8192];   // 32 KB: same layout, rows = hd
  __shared__ __align__(16) float Wb[S_];        // 8 KB log2-domain mask bias
  const int tid = threadIdx.x, wave = tid >> 6, lane = tid & 63;
  const int l31 = lane & 31, hi = lane >> 5, x7 = l31 & 7;
  const int lin = blockIdx.x;
  const int qt = (lin >> 3) & 15;
  const int gi = (lin & 7) + ((lin >> 7) << 3);
  const int h = gi & 15, b = gi >> 4;
  const short* Qh = Q + (size_t)(b * H_ + h) * S_ * HD_;
  const short* Kh = K + (size_t)(b * H_ + h) * S_ * HD_;
  const short* Vh = Vt + (size_t)(b * H_ + h) * HD_ * S_;
  const float* mk = mask + (size_t)b * S_;
  const int q0 = qt * 128 + wave * 32;

  // staging: call i, slot s = tid + i*256 (s in 0..1023 per tensor);
  // sub-tile ts = s>>9, row = (s&511)>>3, chunk = ((s&7) ^ (row&7))
  int srow[4], schk[4], sts[4];
#pragma unroll
  for (int i = 0; i < 4; i++) {
    const int s = tid + i * 256;
    sts[i] = s >> 9;
    const int s9 = s & 511;
    srow[i] = s9 >> 3;
    schk[i] = ((s9 & 7) ^ (srow[i] & 7)) * 8;
  }

  // prologue: stage tile 0 (keys 0..127) into buffer 0
#pragma unroll
  for (int i = 0; i < 4; i++) {
    gld_lds16(Kh + (size_t)(sts[i] * 64 + srow[i]) * HD_ + schk[i],
              &Ks[0][(tid + i * 256) * 8]);
    gld_lds16(Vh + (size_t)srow[i] * S_ + sts[i] * 64 + schk[i],
              &Vs[0][(tid + i * 256) * 8]);
  }

  // mask bias table: 0 for keep, -1.44e8 for masked
  for (int i = tid; i < S_; i += 256)
    Wb[i] = (mk[i] - 1.0f) * MLOG2E;

  // Q as B-operand fragments: qf[c] = Q[q0+l31][c*16 + hi*8 .. +7]
  bf16x8 qf[4];
  {
    const short* qp = Qh + (size_t)(q0 + l31) * HD_ + hi * 8;
#pragma unroll
    for (int c = 0; c < 4; c++) qf[c] = *(const bf16x8*)(qp + c * 16);
  }

  // all-ones bf16 A-fragment for the rowsum MFMA
  bf16x8 ones;
#pragma unroll
  for (int i = 0; i < 8; i++) ones[i] = (short)0x3F80;

  f32x16 acc0, acc1, rsa;
#pragma unroll
  for (int r = 0; r < 16; r++) { acc0[r] = 0.f; acc1[r] = 0.f; rsa[r] = 0.f; }

  // per-lane fragment slot offsets (in shorts): chunk w lives at slot w^x7
  const int kbase = l31 * 64;
  int ko[4];
#pragma unroll
  for (int c = 0; c < 4; c++) ko[c] = ((((c << 1) | hi) ^ x7) << 3);

  __syncthreads();  // tile 0 + bias table staged

  for (int it = 0; it < S_ / 128; it++) {
    const int buf = it & 1;
    const int kt = it * 128;
    if (it + 1 < S_ / 128) {  // issue next 128-key tile's staging
      const int kn = kt + 128;
#pragma unroll
      for (int i = 0; i < 4; i++) {
        gld_lds16(Kh + (size_t)(kn + sts[i] * 64 + srow[i]) * HD_ + schk[i],
                  &Ks[buf ^ 1][(tid + i * 256) * 8]);
        gld_lds16(Vh + (size_t)srow[i] * S_ + kn + sts[i] * 64 + schk[i],
                  &Vs[buf ^ 1][(tid + i * 256) * 8]);
      }
    }

#pragma unroll
    for (int t2 = 0; t2 < 2; t2++) {  // two 64-key sub-tiles per interval
      const int sub = t2 * 4096;
      const int ktt = kt + t2 * 64;

      bf16x8 pB[4];  // PV B-fragments, chunk kc: keys ktt + kc*16 + hi*8 + j
#pragma unroll
      for (int t = 0; t < 2; t++) {
        // bias-seeded C: z[r] = Wb[ktt + t*32 + crow(r,hi)] (broadcast float4s)
        const int kb2 = ktt + t * 32 + 4 * hi;
        const float4 b0 = *(const float4*)&Wb[kb2];
        const float4 b1 = *(const float4*)&Wb[kb2 + 8];
        const float4 b2 = *(const float4*)&Wb[kb2 + 16];
        const float4 b3 = *(const float4*)&Wb[kb2 + 24];
        f32x16 z;
        z[0] = b0.x; z[1] = b0.y; z[2]  = b0.z; z[3]  = b0.w;
        z[4] = b1.x; z[5] = b1.y; z[6]  = b1.z; z[7]  = b1.w;
        z[8] = b2.x; z[9] = b2.y; z[10] = b2.z; z[11] = b2.w;
        z[12] = b3.x; z[13] = b3.y; z[14] = b3.z; z[15] = b3.w;
        const short* kp = &Ks[buf][sub + t * 2048 + kbase];
        __builtin_amdgcn_s_setprio(1);
#pragma unroll
        for (int c = 0; c < 4; c++) {
          const bf16x8 kf = *(const bf16x8*)(kp + ko[c]);
          z = __builtin_amdgcn_mfma_f32_32x32x16_bf16(kf, qf[c], z, 0, 0, 0);
        }
        __builtin_amdgcn_s_setprio(0);
        float p[16];
#pragma unroll
        for (int r = 0; r < 16; r++) p[r] = EXP2(z[r]);
        // pack pairs then half-swap (v2-verified layout):
        int a0 = cvtpk_bf16(p[0], p[1]),   a1 = cvtpk_bf16(p[2], p[3]);
        int cc0 = cvtpk_bf16(p[4], p[5]),  cc1 = cvtpk_bf16(p[6], p[7]);
        int e0 = cvtpk_bf16(p[8], p[9]),   e1 = cvtpk_bf16(p[10], p[11]);
        int g0 = cvtpk_bf16(p[12], p[13]), g1 = cvtpk_bf16(p[14], p[15]);
        swap32(a0, cc0); swap32(a1, cc1);  // -> chunk 2t words {0,1,2,3}
        swap32(e0, g0);  swap32(e1, g1);   // -> chunk 2t+1 words {0,1,2,3}
        union { int i[4]; bf16x8 v; } u0, u1;
        u0.i[0] = a0; u0.i[1] = a1; u0.i[2] = cc0; u0.i[3] = cc1;
        u1.i[0] = e0; u1.i[1] = e1; u1.i[2] = g0;  u1.i[3] = g1;
        pB[t * 2] = u0.v;
        pB[t * 2 + 1] = u1.v;
      }

      // rowsum + PV under raised priority (MFMA cluster)
      const short* vp0 = &Vs[buf][sub + kbase];          // hd rows l31
      const short* vp1 = &Vs[buf][sub + 2048 + kbase];   // hd rows 32+l31
      __builtin_amdgcn_s_setprio(1);
#pragma unroll
      for (int kc = 0; kc < 4; kc++)
        rsa = __builtin_amdgcn_mfma_f32_32x32x16_bf16(ones, pB[kc], rsa, 0, 0, 0);
#pragma unroll
      for (int kc = 0; kc < 4; kc++) {
        const bf16x8 vf0 = *(const bf16x8*)(vp0 + ko[kc]);
        const bf16x8 vf1 = *(const bf16x8*)(vp1 + ko[kc]);
        acc0 = __builtin_amdgcn_mfma_f32_32x32x16_bf16(vf0, pB[kc], acc0, 0, 0, 0);
        acc1 = __builtin_amdgcn_mfma_f32_32x32x16_bf16(vf1, pB[kc], acc1, 0, 0, 0);
      }
      __builtin_amdgcn_s_setprio(0);
    }
    __syncthreads();  // compute reads done; next staging landed
  }

  // epilogue: acc reg r -> ctx[q=l31][hd = d*32 + (r&3) + 8*(r>>2) + 4*hi]
  const float inv = 1.0f / (rsa[0] + 1e-30f);
  const size_t row = (size_t)b * S_ + q0 + l31;
#pragma unroll
  for (int g4 = 0; g4 < 4; g4++) {
    short4v o0, o1;
#pragma unroll
    for (int j = 0; j < 4; j++) {
      o0[j] = f2bf(acc0[g4 * 4 + j] * inv);
      o1[j] = f2bf(acc1[g4 * 4 + j] * inv);
    }
    short* cp = ctx + row * D_ + h * HD_ + g4 * 8 + 4 * hi;
    *(short4v*)(cp) = o0;
    *(short4v*)(cp + 32) = o1;
  }
}

// ---------------- output projection: 64x128 tile, grid 512 (2 blocks/CU) ----
__global__ __launch_bounds__(256, 2)
void gemm_out(const short* __restrict__ X, const short* __restrict__ WT,
              const float* __restrict__ ob, float* __restrict__ out) {
  __shared__ __align__(16) short As[64 * 32];    // 4 KB
  __shared__ __align__(16) short Bs[128 * 32];   // 8 KB
  const int tid = threadIdx.x;
  const int wave = tid >> 6, lane = tid & 63;
  const int col = lane & 15, quad = lane >> 4;
  const int m0 = blockIdx.x * 64;
  const int n0 = blockIdx.y * 128;
  const short* Bsrc = WT + (size_t)n0 * D_;
  const int wrow = (wave & 1) * 32;
  const int wcol = (wave >> 1) * 64;

  floatx4 acc[2][4];
#pragma unroll
  for (int i = 0; i < 2; i++)
#pragma unroll
    for (int j = 0; j < 4; j++) acc[i][j] = floatx4{0.f, 0.f, 0.f, 0.f};

  const int arow = tid >> 2, akcol = (tid & 3) * 8;
  const short* ga = X + (size_t)(m0 + arow) * D_ + akcol;
  const short* gb = Bsrc + (size_t)arow * D_ + akcol;
  short* la = As + tid * 8;
  short* lb = Bs + tid * 8;

  for (int k0 = 0; k0 < D_; k0 += 32) {
    gld_lds16(ga, la);
    gld_lds16(gb, lb);
    gld_lds16(gb + 64 * D_, lb + 2048);
    ga += 32; gb += 32;
    __syncthreads();
    bf16x8 af[2], bfr[4];
#pragma unroll
    for (int i = 0; i < 2; i++)
      af[i] = *(const bf16x8*)(As + (wrow + i * 16 + col) * 32 + quad * 8);
#pragma unroll
    for (int j = 0; j < 4; j++)
      bfr[j] = *(const bf16x8*)(Bs + (wcol + j * 16 + col) * 32 + quad * 8);
#pragma unroll
    for (int i = 0; i < 2; i++)
#pragma unroll
      for (int j = 0; j < 4; j++)
        acc[i][j] = __builtin_amdgcn_mfma_f32_16x16x32_bf16(af[i], bfr[j],
                                                            acc[i][j], 0, 0, 0);
    __syncthreads();
  }

  float bv[4];
#pragma unroll
  for (int j = 0; j < 4; j++) bv[j] = ob[n0 + wcol + j * 16 + col];

#pragma unroll
  for (int i = 0; i < 2; i++) {
    const int m = m0 + wrow + i * 16 + quad * 4;
#pragma unroll
    for (int j = 0; j < 4; j++) {
      const int n = n0 + wcol + j * 16 + col;
#pragma unroll
      for (int r = 0; r < 4; r++)
        out[(size_t)(m + r) * D_ + n] = acc[i][j][r] + bv[j];
    }
  }
}

extern "C" void kernel_launch(void* const* d_in, const int* in_sizes, int n_in,
                              void* d_out, int out_size, void* d_ws, size_t ws_size,
                              hipStream_t stream) {
  (void)in_sizes; (void)n_in; (void)out_size; (void)ws_size;
  const float* hs  = (const float*)d_in[0];
  const float* msk = (const float*)d_in[1];
  const float* qw  = (const float*)d_in[2];
  const float* qb  = (const float*)d_in[3];
  const float* kw  = (const float*)d_in[4];
  const float* kb  = (const float*)d_in[5];
  const float* vw  = (const float*)d_in[6];
  const float* vb  = (const float*)d_in[7];
  const float* ow  = (const float*)d_in[8];
  const float* ob  = (const float*)d_in[9];
  float* out = (float*)d_out;
  char* ws = (char*)d_ws;

  short* Xb  = (short*)(ws);                    // bf16 hs (8 MB); reused as Ctx
  short* WT  = (short*)(ws + (8ull  << 20));    // 4 x 1024x1024 bf16 (8 MB)
  short* Qp  = (short*)(ws + (16ull << 20));    // [B,H,S,HD] (8 MB)
  short* Kp  = (short*)(ws + (24ull << 20));    // [B,H,S,HD] (8 MB)
  short* Vtp = (short*)(ws + (32ull << 20));    // [B,H,HD,S] (8 MB)
  short* Ctx = Xb;                              // [B,S,D] bf16 (overlays Xb)

  prep<<<dim3(16, 16, 5), 256, 0, stream>>>(qw, kw, vw, ow, hs, WT, Xb);
  gemm_qkv<<<dim3(32, 24), 256, 0, stream>>>(Xb, WT, qb, kb, vb, Qp, Kp, Vtp);
  attn<<<dim3(512), 256, 0, stream>>>(Qp, Kp, Vtp, msk, Ctx);
  gemm_out<<<dim3(64, 8), 256, 0, stream>>>(Ctx, WT + 3ull * D_ * D_, ob, out);
}